// Round 3
// baseline (799.782 us; speedup 1.0000x reference)
//
#include <hip/hip_runtime.h>

// ---------------------------------------------------------------------------
// 2-layer GCN, f32 baseline.
//   deg[d] = in-degree(d) + 1 (self loop);  dinv = rsqrt(deg)
//   y'     = (x @ W) * dinv[row]        (GEMM + row scale fused)
//   agg[d] = y'[d] + sum_{e:dst=d} y'[src_e]   (self loop = init value)
//   h[d]   = relu(agg[d]*dinv[d] + b)
// CSC built on device each call (histogram -> scan -> atomic slot fill).
// ---------------------------------------------------------------------------

#define DIM 128

__global__ void k_zero_cnt(int* __restrict__ cnt, int n) {
    int i = blockIdx.x * blockDim.x + threadIdx.x;
    if (i < n) cnt[i] = 0;
}

__global__ void k_hist(const int* __restrict__ dst, int E, int* __restrict__ cnt) {
    int e = blockIdx.x * blockDim.x + threadIdx.x;
    if (e < E) atomicAdd(&cnt[dst[e]], 1);
}

// block sums of cnt (256 elems / block)
__global__ void k_scan_a(const int* __restrict__ cnt, int n, int* __restrict__ bsum) {
    __shared__ int s[256];
    int t = threadIdx.x;
    int i = blockIdx.x * 256 + t;
    s[t] = (i < n) ? cnt[i] : 0;
    __syncthreads();
    for (int off = 128; off > 0; off >>= 1) {
        if (t < off) s[t] += s[t + off];
        __syncthreads();
    }
    if (t == 0) bsum[blockIdx.x] = s[0];
}

// single-block exclusive scan of block sums (nb <= 512)
__global__ void k_scan_b(int* __restrict__ bsum, int nb) {
    __shared__ int s[512];
    int t = threadIdx.x;
    int v = (t < nb) ? bsum[t] : 0;
    s[t] = v;
    __syncthreads();
    for (int off = 1; off < 512; off <<= 1) {
        int tv = (t >= off) ? s[t - off] : 0;
        __syncthreads();
        s[t] += tv;
        __syncthreads();
    }
    if (t < nb) bsum[t] = s[t] - v;   // exclusive
}

// per-block exclusive scan + global offset -> rowptr, pos; also dinv
__global__ void k_scan_c(const int* __restrict__ cnt, int n,
                         const int* __restrict__ boff,
                         int* __restrict__ rowptr, int* __restrict__ pos,
                         float* __restrict__ dinv) {
    __shared__ int s[256];
    int t = threadIdx.x;
    int i = blockIdx.x * 256 + t;
    int v = (i < n) ? cnt[i] : 0;
    s[t] = v;
    __syncthreads();
    for (int off = 1; off < 256; off <<= 1) {
        int tv = (t >= off) ? s[t - off] : 0;
        __syncthreads();
        s[t] += tv;
        __syncthreads();
    }
    int excl = s[t] - v + boff[blockIdx.x];
    if (i < n) {
        rowptr[i] = excl;
        pos[i]    = excl;
        dinv[i]   = rsqrtf((float)(v + 1));   // +1 self loop; always > 0
        if (i == n - 1) rowptr[n] = excl + v;
    }
}

__global__ void k_fill(const int* __restrict__ src, const int* __restrict__ dst,
                       int E, int* __restrict__ pos, int* __restrict__ col) {
    int e = blockIdx.x * blockDim.x + threadIdx.x;
    if (e < E) {
        int slot = atomicAdd(&pos[dst[e]], 1);
        col[slot] = src[e];
    }
}

// y[i][j] = dinv[i] * sum_k x[i][k] * W[k][j]
// block: 256 threads, 8 rows/iter, 4 cols/thread. W (64KB) + 8 x-rows in LDS.
// grid-stride over row tiles so W staging amortizes over ~6 tiles/block.
__global__ __launch_bounds__(256, 2) void k_gemm_scale(
    const float* __restrict__ x, const float* __restrict__ W,
    const float* __restrict__ dinv, float* __restrict__ y, int n) {
    __shared__ float Ws[DIM * DIM];
    __shared__ float xs[8][DIM];
    int t = threadIdx.x;

    // stage W once (coalesced float4)
    {
        const float4* W4 = (const float4*)W;
        float4* Ws4 = (float4*)Ws;
        for (int i = t; i < DIM * DIM / 4; i += 256) Ws4[i] = W4[i];
    }
    __syncthreads();

    int c = t & 31;    // column base (cols c, c+32, c+64, c+96)
    int r = t >> 5;    // row 0..7 within tile

    for (int row0 = blockIdx.x * 8; row0 < n; row0 += gridDim.x * 8) {
        // stage 8 rows of x: thread t loads float4 (row t>>5, quad t&31)
        {
            int g = row0 + (t >> 5);
            float4 v = (g < n) ? ((const float4*)x)[(size_t)g * 32 + (t & 31)]
                               : make_float4(0.f, 0.f, 0.f, 0.f);
            ((float4*)xs)[t] = v;
        }
        __syncthreads();

        float a0 = 0.f, a1 = 0.f, a2 = 0.f, a3 = 0.f;
#pragma unroll 4
        for (int k = 0; k < DIM; ++k) {
            float xv = xs[r][k];
            a0 += xv * Ws[k * DIM + c];
            a1 += xv * Ws[k * DIM + c + 32];
            a2 += xv * Ws[k * DIM + c + 64];
            a3 += xv * Ws[k * DIM + c + 96];
        }

        int row = row0 + r;
        if (row < n) {
            float dv = dinv[row];
            float* yr = y + (size_t)row * DIM;
            yr[c]      = a0 * dv;
            yr[c + 32] = a1 * dv;
            yr[c + 64] = a2 * dv;
            yr[c + 96] = a3 * dv;
        }
        __syncthreads();  // protect xs before next stage
    }
}

// aggregation: one 32-lane half-wave per node, float4 per lane.
// out[d] = relu(dinv[d] * (y'[d] + sum_in y'[src]) + bias)
__global__ __launch_bounds__(256) void k_agg(
    const float* __restrict__ y, const int* __restrict__ rowptr,
    const int* __restrict__ col, const float* __restrict__ dinv,
    const float* __restrict__ bias, float* __restrict__ out, int n) {
    int t = threadIdx.x;
    int lane = t & 31;
    int node = blockIdx.x * 8 + (t >> 5);
    if (node >= n) return;

    const float4* y4 = (const float4*)y;
    int lo = rowptr[node];
    int hi = rowptr[node + 1];

    float4 acc = y4[(size_t)node * 32 + lane];   // self loop
    for (int i = lo; i < hi; ++i) {
        int s = col[i];
        float4 v = y4[(size_t)s * 32 + lane];
        acc.x += v.x; acc.y += v.y; acc.z += v.z; acc.w += v.w;
    }

    float dv = dinv[node];
    float4 b = ((const float4*)bias)[lane];
    float4 o;
    o.x = fmaxf(acc.x * dv + b.x, 0.f);
    o.y = fmaxf(acc.y * dv + b.y, 0.f);
    o.z = fmaxf(acc.z * dv + b.z, 0.f);
    o.w = fmaxf(acc.w * dv + b.w, 0.f);
    ((float4*)out)[(size_t)node * 32 + lane] = o;
}

extern "C" void kernel_launch(void* const* d_in, const int* in_sizes, int n_in,
                              void* d_out, int out_size, void* d_ws, size_t ws_size,
                              hipStream_t stream) {
    const float* x  = (const float*)d_in[0];
    const float* W1 = (const float*)d_in[1];
    const float* b1 = (const float*)d_in[2];
    const float* W2 = (const float*)d_in[3];
    const float* b2 = (const float*)d_in[4];
    const int*   ei = (const int*)d_in[5];

    const int n = in_sizes[0] / DIM;     // 100000
    const int E = in_sizes[5] / 2;       // 1600000
    const int* src = ei;
    const int* dst = ei + E;
    float* out = (float*)d_out;

    // workspace carve-up (all 4B types; y first for 16B alignment)
    char* w = (char*)d_ws;
    float* y      = (float*)w;  w += (size_t)n * DIM * sizeof(float);   // 51.2 MB
    float* dinv   = (float*)w;  w += (size_t)n * sizeof(float);
    int*   cnt    = (int*)w;    w += (size_t)n * sizeof(int);
    int*   rowptr = (int*)w;    w += (size_t)(n + 1) * sizeof(int);
    int*   pos    = (int*)w;    w += (size_t)n * sizeof(int);
    int*   colsrc = (int*)w;    w += (size_t)E * sizeof(int);           // 6.4 MB
    int*   bsum   = (int*)w;    w += 512 * sizeof(int);

    const int nbN    = (n + 255) / 256;   // 391
    const int nbE    = (E + 255) / 256;   // 6250
    const int nbAgg  = (n + 7) / 8;       // 12500
    const int nbGemm = 2048;              // grid-stride; ~6 row-tiles per block

    // ---- CSC + dinv -------------------------------------------------------
    k_zero_cnt<<<nbN, 256, 0, stream>>>(cnt, n);
    k_hist<<<nbE, 256, 0, stream>>>(dst, E, cnt);
    k_scan_a<<<nbN, 256, 0, stream>>>(cnt, n, bsum);
    k_scan_b<<<1, 512, 0, stream>>>(bsum, nbN);
    k_scan_c<<<nbN, 256, 0, stream>>>(cnt, n, bsum, rowptr, pos, dinv);
    k_fill<<<nbE, 256, 0, stream>>>(src, dst, E, pos, colsrc);

    // ---- layer 1: y = (x@W1)*dinv ; out(=h1) = relu(agg*dinv + b1) --------
    k_gemm_scale<<<nbGemm, 256, 0, stream>>>(x, W1, dinv, y, n);
    k_agg<<<nbAgg, 256, 0, stream>>>(y, rowptr, colsrc, dinv, b1, out, n);

    // ---- layer 2: y = (h1@W2)*dinv ; out = relu(agg*dinv + b2) ------------
    k_gemm_scale<<<nbGemm, 256, 0, stream>>>(out, W2, dinv, y, n);
    k_agg<<<nbAgg, 256, 0, stream>>>(y, rowptr, colsrc, dinv, b2, out, n);
}

// Round 4
// 588.887 us; speedup vs baseline: 1.3581x; 1.3581x over previous
//
#include <hip/hip_runtime.h>
#include <hip/hip_bf16.h>

// ---------------------------------------------------------------------------
// 2-layer GCN. MFMA bf16 GEMM with W-split compensation, bf16 message buffer.
//   dinv = rsqrt(deg+1);  y' = bf16( (x_bf16 @ (Whi+Wlo)) * dinv[row] )
//   agg[d] = y'[d] + sum y'[src];  h = relu(agg*dinv + b)  (h stored bf16;
//   final layer writes f32 to d_out)
// CSC built on device (histogram -> scan -> atomic slot fill).
// ---------------------------------------------------------------------------

#define DIM 128

typedef __attribute__((ext_vector_type(8))) short bf16x8;
typedef __attribute__((ext_vector_type(4))) float f32x4;

// ---------------- CSC build (unchanged from verified round 3) --------------

__global__ void k_zero_cnt(int* __restrict__ cnt, int n) {
    int i = blockIdx.x * blockDim.x + threadIdx.x;
    if (i < n) cnt[i] = 0;
}

__global__ void k_hist(const int* __restrict__ dst, int E, int* __restrict__ cnt) {
    int e = blockIdx.x * blockDim.x + threadIdx.x;
    if (e < E) atomicAdd(&cnt[dst[e]], 1);
}

__global__ void k_scan_a(const int* __restrict__ cnt, int n, int* __restrict__ bsum) {
    __shared__ int s[256];
    int t = threadIdx.x;
    int i = blockIdx.x * 256 + t;
    s[t] = (i < n) ? cnt[i] : 0;
    __syncthreads();
    for (int off = 128; off > 0; off >>= 1) {
        if (t < off) s[t] += s[t + off];
        __syncthreads();
    }
    if (t == 0) bsum[blockIdx.x] = s[0];
}

__global__ void k_scan_b(int* __restrict__ bsum, int nb) {
    __shared__ int s[512];
    int t = threadIdx.x;
    int v = (t < nb) ? bsum[t] : 0;
    s[t] = v;
    __syncthreads();
    for (int off = 1; off < 512; off <<= 1) {
        int tv = (t >= off) ? s[t - off] : 0;
        __syncthreads();
        s[t] += tv;
        __syncthreads();
    }
    if (t < nb) bsum[t] = s[t] - v;   // exclusive
}

__global__ void k_scan_c(const int* __restrict__ cnt, int n,
                         const int* __restrict__ boff,
                         int* __restrict__ rowptr, int* __restrict__ pos,
                         float* __restrict__ dinv) {
    __shared__ int s[256];
    int t = threadIdx.x;
    int i = blockIdx.x * 256 + t;
    int v = (i < n) ? cnt[i] : 0;
    s[t] = v;
    __syncthreads();
    for (int off = 1; off < 256; off <<= 1) {
        int tv = (t >= off) ? s[t - off] : 0;
        __syncthreads();
        s[t] += tv;
        __syncthreads();
    }
    int excl = s[t] - v + boff[blockIdx.x];
    if (i < n) {
        rowptr[i] = excl;
        pos[i]    = excl;
        dinv[i]   = rsqrtf((float)(v + 1));
        if (i == n - 1) rowptr[n] = excl + v;
    }
}

__global__ void k_fill(const int* __restrict__ src, const int* __restrict__ dst,
                       int E, int* __restrict__ pos, int* __restrict__ col) {
    int e = blockIdx.x * blockDim.x + threadIdx.x;
    if (e < E) {
        int slot = atomicAdd(&pos[dst[e]], 1);
        col[slot] = src[e];
    }
}

// ---------------- precision prep ------------------------------------------

// x f32 -> bf16 (RNE), 4 elems/thread
__global__ void k_cast_x(const float* __restrict__ x, ushort* __restrict__ xb,
                         int total4) {
    int i = blockIdx.x * 256 + threadIdx.x;
    if (i < total4) {
        float4 v = ((const float4*)x)[i];
        __hip_bfloat16 a = __float2bfloat16(v.x), b = __float2bfloat16(v.y);
        __hip_bfloat16 c = __float2bfloat16(v.z), d = __float2bfloat16(v.w);
        ushort4 o = make_ushort4(*(ushort*)&a, *(ushort*)&b,
                                 *(ushort*)&c, *(ushort*)&d);
        ((ushort4*)xb)[i] = o;
    }
}

// W [128][128] f32 -> packed MFMA B-fragments, hi+lo split.
// Wpk layout (ushort): [term(2)][ct(8)][ks(4)][lane(64)][j(8)]  = 64 KB
// fragment mapping (m89-verified family): B[k = ks*32 + (lane>>4)*8 + j]
//                                          [n = ct*16 + (lane&15)]
__global__ void k_split_w(const float* __restrict__ W, ushort* __restrict__ Wpk) {
    int idx = blockIdx.x * 256 + threadIdx.x;   // 0..16383
    if (idx >= 16384) return;
    int j    = idx & 7;
    int lane = (idx >> 3) & 63;
    int ks   = (idx >> 9) & 3;
    int ct   = idx >> 11;
    int k  = ks * 32 + (lane >> 4) * 8 + j;
    int nn = ct * 16 + (lane & 15);
    float w = W[k * 128 + nn];
    __hip_bfloat16 hi = __float2bfloat16(w);
    float rem = w - __bfloat162float(hi);
    __hip_bfloat16 lo = __float2bfloat16(rem);
    Wpk[idx]         = *(ushort*)&hi;
    Wpk[16384 + idx] = *(ushort*)&lo;
}

// ---------------- MFMA GEMM: y = bf16( (xb @ (Whi+Wlo)) * dinv[row] ) ------
// block = 256 thr (4 waves). Block tile = 64 rows x 128 cols, K=128.
// Wave w: rows [tile*64 + 16w, +16). A-frags direct from global (16B/lane).
// Packed W staged in LDS (64 KB) once per block; grid-stride over tiles.
__global__ __launch_bounds__(256, 2) void k_gemm_mfma(
    const ushort* __restrict__ xb, const ushort* __restrict__ Wpk,
    const float* __restrict__ dinv, ushort* __restrict__ y,
    int n, int ntiles) {
    __shared__ ushort Wl[32768];   // [term][ct][ks][lane][j]
    int t = threadIdx.x;
    {
        const uint4* s4 = (const uint4*)Wpk;
        uint4* d4 = (uint4*)Wl;
#pragma unroll
        for (int i = 0; i < 16; ++i) d4[t + 256 * i] = s4[t + 256 * i];
    }
    __syncthreads();

    const int wave = t >> 6, lane = t & 63;
    const int l15 = lane & 15, lg = lane >> 4;

    for (int tile = blockIdx.x; tile < ntiles; tile += gridDim.x) {
        int row0 = tile * 64 + wave * 16;
        int arow = row0 + l15;
        if (arow >= n) arow = n - 1;              // tail clamp (stores guarded)
        const ushort* xp = xb + (size_t)arow * 128 + lg * 8;

        bf16x8 a[4];
#pragma unroll
        for (int ks = 0; ks < 4; ++ks)
            a[ks] = *(const bf16x8*)(xp + ks * 32);

        f32x4 acc[8];
#pragma unroll
        for (int ct = 0; ct < 8; ++ct) acc[ct] = (f32x4)(0.f);

#pragma unroll
        for (int ks = 0; ks < 4; ++ks) {
#pragma unroll
            for (int ct = 0; ct < 8; ++ct) {      // hi term
                bf16x8 b = *(const bf16x8*)&Wl[(size_t)((0 * 8 + ct) * 4 + ks) * 512 + lane * 8];
                acc[ct] = __builtin_amdgcn_mfma_f32_16x16x32_bf16(a[ks], b, acc[ct], 0, 0, 0);
            }
#pragma unroll
            for (int ct = 0; ct < 8; ++ct) {      // lo term
                bf16x8 b = *(const bf16x8*)&Wl[(size_t)((1 * 8 + ct) * 4 + ks) * 512 + lane * 8];
                acc[ct] = __builtin_amdgcn_mfma_f32_16x16x32_bf16(a[ks], b, acc[ct], 0, 0, 0);
            }
        }

        // D: row = row0 + 4*lg + r, col = ct*16 + l15
#pragma unroll
        for (int r = 0; r < 4; ++r) {
            int row = row0 + lg * 4 + r;
            if (row < n) {
                float dv = dinv[row];
                ushort* yr = y + (size_t)row * 128 + l15;
#pragma unroll
                for (int ct = 0; ct < 8; ++ct) {
                    __hip_bfloat16 h = __float2bfloat16(acc[ct][r] * dv);
                    yr[ct * 16] = *(ushort*)&h;
                }
            }
        }
    }
}

// ---------------- aggregation: full wave per node, bf16 rows ---------------
// out[d] = relu(dinv[d]*(y'[d] + sum_in y'[src]) + b) ; MODE 0: bf16 h out,
// MODE 1: f32 out (final).
template <int MODE>
__global__ __launch_bounds__(256) void k_agg2(
    const ushort* __restrict__ yb, const int* __restrict__ rowptr,
    const int* __restrict__ col, const float* __restrict__ dinv,
    const float* __restrict__ bias, void* __restrict__ outp, int n) {
    int t = threadIdx.x, lane = t & 63;
    int node = blockIdx.x * 4 + (t >> 6);
    if (node >= n) return;

    // self loop: row 'node'
    uint v0 = *(const uint*)(yb + (size_t)node * 128 + lane * 2);
    float ax = __uint_as_float(v0 << 16);
    float ay = __uint_as_float(v0 & 0xffff0000u);

    int lo = rowptr[node], hi = rowptr[node + 1];
    for (int base = lo; base < hi; base += 64) {
        int cv = (base + lane < hi) ? col[base + lane] : 0;
        int m = hi - base; if (m > 64) m = 64;
        for (int i = 0; i < m; ++i) {
            int s = __shfl(cv, i);
            uint v = *(const uint*)(yb + (size_t)s * 128 + lane * 2);
            ax += __uint_as_float(v << 16);
            ay += __uint_as_float(v & 0xffff0000u);
        }
    }

    float dv = dinv[node];
    float2 b = ((const float2*)bias)[lane];
    float ox = fmaxf(ax * dv + b.x, 0.f);
    float oy = fmaxf(ay * dv + b.y, 0.f);

    if (MODE == 0) {
        __hip_bfloat16 ha = __float2bfloat16(ox), hb = __float2bfloat16(oy);
        uint o = ((uint)(*(ushort*)&hb) << 16) | (uint)(*(ushort*)&ha);
        ((uint*)outp)[(size_t)node * 64 + lane] = o;
    } else {
        ((float2*)outp)[(size_t)node * 64 + lane] = make_float2(ox, oy);
    }
}

// ---------------------------------------------------------------------------

extern "C" void kernel_launch(void* const* d_in, const int* in_sizes, int n_in,
                              void* d_out, int out_size, void* d_ws, size_t ws_size,
                              hipStream_t stream) {
    const float* x  = (const float*)d_in[0];
    const float* W1 = (const float*)d_in[1];
    const float* b1 = (const float*)d_in[2];
    const float* W2 = (const float*)d_in[3];
    const float* b2 = (const float*)d_in[4];
    const int*   ei = (const int*)d_in[5];

    const int n = in_sizes[0] / DIM;     // 100000
    const int E = in_sizes[5] / 2;       // 1600000
    const int* src = ei;
    const int* dst = ei + E;
    float* out = (float*)d_out;

    // workspace carve-up (16B-aligned chunks)
    char* w = (char*)d_ws;
    ushort* xb   = (ushort*)w;  w += (size_t)n * DIM * sizeof(ushort);   // 25.6 MB (also y)
    ushort* h    = (ushort*)w;  w += (size_t)n * DIM * sizeof(ushort);   // 25.6 MB
    ushort* wpk1 = (ushort*)w;  w += 32768 * sizeof(ushort);             // 64 KB
    ushort* wpk2 = (ushort*)w;  w += 32768 * sizeof(ushort);             // 64 KB
    float* dinv  = (float*)w;   w += (size_t)n * sizeof(float);
    int*   cnt   = (int*)w;     w += (size_t)n * sizeof(int);
    int*   rowptr= (int*)w;     w += (size_t)(n + 4) * sizeof(int);
    int*   pos   = (int*)w;     w += (size_t)n * sizeof(int);
    int*   colsrc= (int*)w;     w += (size_t)E * sizeof(int);            // 6.4 MB
    int*   bsum  = (int*)w;     w += 512 * sizeof(int);

    ushort* y = xb;  // safe alias: gemm reads its rows before storing them

    const int nbN    = (n + 255) / 256;      // 391
    const int nbE    = (E + 255) / 256;      // 6250
    const int nbAgg  = (n + 3) / 4;          // 25000
    const int ntiles = (n + 63) / 64;        // 1563
    const int nbGemm = 512;                  // 2 blocks/CU, ~3 tiles each
    const int nbCast = (n * DIM / 4 + 255) / 256;

    // ---- CSC + dinv -------------------------------------------------------
    k_zero_cnt<<<nbN, 256, 0, stream>>>(cnt, n);
    k_hist<<<nbE, 256, 0, stream>>>(dst, E, cnt);
    k_scan_a<<<nbN, 256, 0, stream>>>(cnt, n, bsum);
    k_scan_b<<<1, 512, 0, stream>>>(bsum, nbN);
    k_scan_c<<<nbN, 256, 0, stream>>>(cnt, n, bsum, rowptr, pos, dinv);
    k_fill<<<nbE, 256, 0, stream>>>(src, dst, E, pos, colsrc);

    // ---- precision prep ---------------------------------------------------
    k_split_w<<<64, 256, 0, stream>>>(W1, wpk1);
    k_split_w<<<64, 256, 0, stream>>>(W2, wpk2);
    k_cast_x<<<nbCast, 256, 0, stream>>>(x, xb, n * DIM / 4);

    // ---- layer 1 ----------------------------------------------------------
    k_gemm_mfma<<<nbGemm, 256, 0, stream>>>(xb, wpk1, dinv, y, n, ntiles);
    k_agg2<0><<<nbAgg, 256, 0, stream>>>(y, rowptr, colsrc, dinv, b1, h, n);

    // ---- layer 2 ----------------------------------------------------------
    k_gemm_mfma<<<nbGemm, 256, 0, stream>>>(h, wpk2, dinv, y, n, ntiles);
    k_agg2<1><<<nbAgg, 256, 0, stream>>>(y, rowptr, colsrc, dinv, b2, out, n);
}

// Round 5
// 559.051 us; speedup vs baseline: 1.4306x; 1.0534x over previous
//
#include <hip/hip_runtime.h>
#include <hip/hip_bf16.h>

// ---------------------------------------------------------------------------
// 2-layer GCN. MFMA bf16 GEMM (W hi+lo split), bf16 messages, bucket-built CSC.
//   dinv = rsqrt(deg+1);  y' = bf16( (x_bf16 @ (Whi+Wlo)) * dinv[row] )
//   agg[d] = y'[d] + sum y'[src];  h = relu(agg*dinv + b)
// CSC: bucket count -> scan -> write-combined bucket scatter -> per-bucket CSC.
// ---------------------------------------------------------------------------

#define DIM 128
#define BSH 9                    // bucket shift: 512 dst/bucket
#define NBKT 196                 // ceil(100000 / 512)

typedef __attribute__((ext_vector_type(8))) short bf16x8;
typedef __attribute__((ext_vector_type(4))) float f32x4;

// ---------------- bucket CSC pipeline --------------------------------------

// A: per-bucket edge counts (LDS histogram, one global atomic per bucket/block)
__global__ __launch_bounds__(256) void k_bcount(const int* __restrict__ dst,
                                                int E, int* __restrict__ bcnt) {
    __shared__ int h[NBKT];
    int t = threadIdx.x;
    for (int b = t; b < NBKT; b += 256) h[b] = 0;
    __syncthreads();
    for (int e = blockIdx.x * 256 + t; e < E; e += gridDim.x * 256)
        atomicAdd(&h[dst[e] >> BSH], 1);
    __syncthreads();
    for (int b = t; b < NBKT; b += 256)
        if (h[b]) atomicAdd(&bcnt[b], h[b]);
}

// B: exclusive scan of bcnt -> bbase[NBKT+1], init bcur
__global__ void k_bscan(const int* __restrict__ bcnt, int* __restrict__ bbase,
                        int* __restrict__ bcur) {
    __shared__ int a[256], c[256];
    int t = threadIdx.x;
    int v = (t < NBKT) ? bcnt[t] : 0;
    a[t] = v;
    __syncthreads();
    int* A = a; int* B = c;
    for (int off = 1; off < 256; off <<= 1) {
        B[t] = A[t] + (t >= off ? A[t - off] : 0);
        __syncthreads();
        int* tmp = A; A = B; B = tmp;
    }
    int incl = A[t];                 // 8 steps -> result back in 'a'
    if (t < NBKT) { int ex = incl - v; bbase[t] = ex; bcur[t] = ex; }
    if (t == NBKT - 1) bbase[NBKT] = incl;
}

// C: scatter (dst,src) pairs into bucket-grouped order, write-combined via LDS.
// Full 16-entry (128B) chunks flushed to atomically reserved contiguous slots.
__global__ __launch_bounds__(256) void k_bscatter(
    const int* __restrict__ src, const int* __restrict__ dst, int E,
    int* __restrict__ bcur, uint2* __restrict__ out) {
    __shared__ uint2 stage[NBKT * 16];
    __shared__ int scnt[NBKT];
    int t = threadIdx.x;
    for (int b = t; b < NBKT; b += 256) scnt[b] = 0;
    __syncthreads();

    int per = (E + gridDim.x - 1) / gridDim.x;
    int s0 = blockIdx.x * per;
    int s1 = min(E, s0 + per);

    for (int base = s0; base < s1; base += 256) {
        int e = base + t;
        if (e < s1) {
            int d = dst[e];
            uint2 pr; pr.x = (uint)d; pr.y = (uint)src[e];
            int b = d >> BSH;
            int slot = atomicAdd(&scnt[b], 1);
            if (slot < 16) stage[b * 16 + slot] = pr;
            else { int c = atomicAdd(&bcur[b], 1); out[c] = pr; }  // rare
        }
        __syncthreads();
        for (int bb = t; bb < NBKT; bb += 256) {
            int c = scnt[bb];
            if (c >= 16) {
                int cur = atomicAdd(&bcur[bb], 16);
#pragma unroll
                for (int k = 0; k < 16; ++k) out[cur + k] = stage[bb * 16 + k];
                scnt[bb] = 0;
            }
        }
        __syncthreads();
    }
    for (int bb = t; bb < NBKT; bb += 256) {
        int c = scnt[bb]; if (c > 16) c = 16;
        if (c > 0) {
            int cur = atomicAdd(&bcur[bb], c);
            for (int k = 0; k < c; ++k) out[cur + k] = stage[bb * 16 + k];
        }
    }
}

// D: per bucket: local hist + scan -> rowptr/dinv (coalesced), col scatter
// within the bucket's contiguous window (write-combined in one L2).
__global__ __launch_bounds__(256) void k_bcsc(
    const uint2* __restrict__ pairs, const int* __restrict__ bbase,
    int* __restrict__ rowptr, float* __restrict__ dinv,
    int* __restrict__ col, int n) {
    __shared__ int lh[512], ls[512];
    int b = blockIdx.x, t = threadIdx.x;
    int p0 = bbase[b], p1 = bbase[b + 1];
    int d0 = b << BSH;

    lh[t] = 0; lh[t + 256] = 0;
    __syncthreads();
    for (int i = p0 + t; i < p1; i += 256)
        atomicAdd(&lh[pairs[i].x & 511], 1);
    __syncthreads();

    int deg0 = lh[t], deg1 = lh[t + 256];
    int* A = lh; int* B = ls;
    for (int off = 1; off < 512; off <<= 1) {      // 9 steps -> incl in ls
        B[t]       = A[t]       + (t       >= off ? A[t - off]       : 0);
        B[t + 256] = A[t + 256] + (t + 256 >= off ? A[t + 256 - off] : 0);
        __syncthreads();
        int* tmp = A; A = B; B = tmp;
    }
    int ex0 = A[t] - deg0, ex1 = A[t + 256] - deg1;
    __syncthreads();
    B[t] = ex0; B[t + 256] = ex1;                  // B == lh: cursors

    int nd = d0 + t;
    if (nd < n) { rowptr[nd] = p0 + ex0; dinv[nd] = rsqrtf((float)(deg0 + 1)); }
    nd = d0 + t + 256;
    if (nd < n) { rowptr[nd] = p0 + ex1; dinv[nd] = rsqrtf((float)(deg1 + 1)); }
    if (b == NBKT - 1 && t == 0) rowptr[n] = p1;
    __syncthreads();

    for (int i = p0 + t; i < p1; i += 256) {
        uint2 pr = pairs[i];
        int slot = p0 + atomicAdd(&B[pr.x & 511], 1);
        col[slot] = (int)pr.y;
    }
}

// ---------------- precision prep ------------------------------------------

__global__ void k_cast_x(const float* __restrict__ x, ushort* __restrict__ xb,
                         int total4) {
    int i = blockIdx.x * 256 + threadIdx.x;
    if (i < total4) {
        float4 v = ((const float4*)x)[i];
        __hip_bfloat16 a = __float2bfloat16(v.x), b = __float2bfloat16(v.y);
        __hip_bfloat16 c = __float2bfloat16(v.z), d = __float2bfloat16(v.w);
        ushort4 o = make_ushort4(*(ushort*)&a, *(ushort*)&b,
                                 *(ushort*)&c, *(ushort*)&d);
        ((ushort4*)xb)[i] = o;
    }
}

// W [128][128] f32 -> packed MFMA B-fragments, hi+lo split.
// Wpk (ushort): [term(2)][ct(8)][ks(4)][lane(64)][j(8)]
// B[k = ks*32 + (lane>>4)*8 + j][n = ct*16 + (lane&15)]
__global__ void k_split_w(const float* __restrict__ W, ushort* __restrict__ Wpk) {
    int idx = blockIdx.x * 256 + threadIdx.x;   // 0..16383
    if (idx >= 16384) return;
    int j    = idx & 7;
    int lane = (idx >> 3) & 63;
    int ks   = (idx >> 9) & 3;
    int ct   = idx >> 11;
    int k  = ks * 32 + (lane >> 4) * 8 + j;
    int nn = ct * 16 + (lane & 15);
    float w = W[k * 128 + nn];
    __hip_bfloat16 hi = __float2bfloat16(w);
    float rem = w - __bfloat162float(hi);
    __hip_bfloat16 lo = __float2bfloat16(rem);
    Wpk[idx]         = *(ushort*)&hi;
    Wpk[16384 + idx] = *(ushort*)&lo;
}

// ---------------- MFMA GEMM: y = bf16( (xb @ (Whi+Wlo)) * dinv[row] ) ------
__global__ __launch_bounds__(256, 2) void k_gemm_mfma(
    const ushort* __restrict__ xb, const ushort* __restrict__ Wpk,
    const float* __restrict__ dinv, ushort* __restrict__ y,
    int n, int ntiles) {
    __shared__ ushort Wl[32768];
    int t = threadIdx.x;
    {
        const uint4* s4 = (const uint4*)Wpk;
        uint4* d4 = (uint4*)Wl;
#pragma unroll
        for (int i = 0; i < 16; ++i) d4[t + 256 * i] = s4[t + 256 * i];
    }
    __syncthreads();

    const int wave = t >> 6, lane = t & 63;
    const int l15 = lane & 15, lg = lane >> 4;

    for (int tile = blockIdx.x; tile < ntiles; tile += gridDim.x) {
        int row0 = tile * 64 + wave * 16;
        int arow = row0 + l15;
        if (arow >= n) arow = n - 1;
        const ushort* xp = xb + (size_t)arow * 128 + lg * 8;

        bf16x8 a[4];
#pragma unroll
        for (int ks = 0; ks < 4; ++ks)
            a[ks] = *(const bf16x8*)(xp + ks * 32);

        f32x4 acc[8];
#pragma unroll
        for (int ct = 0; ct < 8; ++ct) acc[ct] = (f32x4)(0.f);

#pragma unroll
        for (int ks = 0; ks < 4; ++ks) {
#pragma unroll
            for (int ct = 0; ct < 8; ++ct) {
                bf16x8 b = *(const bf16x8*)&Wl[(size_t)((0 * 8 + ct) * 4 + ks) * 512 + lane * 8];
                acc[ct] = __builtin_amdgcn_mfma_f32_16x16x32_bf16(a[ks], b, acc[ct], 0, 0, 0);
            }
#pragma unroll
            for (int ct = 0; ct < 8; ++ct) {
                bf16x8 b = *(const bf16x8*)&Wl[(size_t)((1 * 8 + ct) * 4 + ks) * 512 + lane * 8];
                acc[ct] = __builtin_amdgcn_mfma_f32_16x16x32_bf16(a[ks], b, acc[ct], 0, 0, 0);
            }
        }

#pragma unroll
        for (int r = 0; r < 4; ++r) {
            int row = row0 + lg * 4 + r;
            if (row < n) {
                float dv = dinv[row];
                ushort* yr = y + (size_t)row * 128 + l15;
#pragma unroll
                for (int ct = 0; ct < 8; ++ct) {
                    __hip_bfloat16 h = __float2bfloat16(acc[ct][r] * dv);
                    yr[ct * 16] = *(ushort*)&h;
                }
            }
        }
    }
}

// ---------------- aggregation: full wave per node, 4 gathers in flight -----
template <int MODE>   // 0: bf16 out, 1: f32 out
__global__ __launch_bounds__(256) void k_agg2(
    const ushort* __restrict__ yb, const int* __restrict__ rowptr,
    const int* __restrict__ col, const float* __restrict__ dinv,
    const float* __restrict__ bias, void* __restrict__ outp, int n) {
    int t = threadIdx.x, lane = t & 63;
    int node = blockIdx.x * 4 + (t >> 6);
    if (node >= n) return;

    uint v0 = *(const uint*)(yb + (size_t)node * 128 + lane * 2);   // self loop
    float ax = __uint_as_float(v0 << 16);
    float ay = __uint_as_float(v0 & 0xffff0000u);

    int lo = rowptr[node], hi = rowptr[node + 1];
    int i = lo;
    for (; i + 4 <= hi; i += 4) {
        int s0 = col[i], s1 = col[i + 1], s2 = col[i + 2], s3 = col[i + 3];
        uint w0 = *(const uint*)(yb + (size_t)s0 * 128 + lane * 2);
        uint w1 = *(const uint*)(yb + (size_t)s1 * 128 + lane * 2);
        uint w2 = *(const uint*)(yb + (size_t)s2 * 128 + lane * 2);
        uint w3 = *(const uint*)(yb + (size_t)s3 * 128 + lane * 2);
        ax += __uint_as_float(w0 << 16);         ay += __uint_as_float(w0 & 0xffff0000u);
        ax += __uint_as_float(w1 << 16);         ay += __uint_as_float(w1 & 0xffff0000u);
        ax += __uint_as_float(w2 << 16);         ay += __uint_as_float(w2 & 0xffff0000u);
        ax += __uint_as_float(w3 << 16);         ay += __uint_as_float(w3 & 0xffff0000u);
    }
    for (; i < hi; ++i) {
        int s = col[i];
        uint w = *(const uint*)(yb + (size_t)s * 128 + lane * 2);
        ax += __uint_as_float(w << 16);
        ay += __uint_as_float(w & 0xffff0000u);
    }

    float dv = dinv[node];
    float2 b = ((const float2*)bias)[lane];
    float ox = fmaxf(ax * dv + b.x, 0.f);
    float oy = fmaxf(ay * dv + b.y, 0.f);

    if (MODE == 0) {
        __hip_bfloat16 ha = __float2bfloat16(ox), hb = __float2bfloat16(oy);
        uint o = ((uint)(*(ushort*)&hb) << 16) | (uint)(*(ushort*)&ha);
        ((uint*)outp)[(size_t)node * 64 + lane] = o;
    } else {
        ((float2*)outp)[(size_t)node * 64 + lane] = make_float2(ox, oy);
    }
}

// ---------------------------------------------------------------------------

extern "C" void kernel_launch(void* const* d_in, const int* in_sizes, int n_in,
                              void* d_out, int out_size, void* d_ws, size_t ws_size,
                              hipStream_t stream) {
    const float* x  = (const float*)d_in[0];
    const float* W1 = (const float*)d_in[1];
    const float* b1 = (const float*)d_in[2];
    const float* W2 = (const float*)d_in[3];
    const float* b2 = (const float*)d_in[4];
    const int*   ei = (const int*)d_in[5];

    const int n = in_sizes[0] / DIM;     // 100000
    const int E = in_sizes[5] / 2;       // 1600000
    const int* src = ei;
    const int* dst = ei + E;
    float* out = (float*)d_out;

    // workspace carve-up
    char* w = (char*)d_ws;
    ushort* xb    = (ushort*)w;  w += (size_t)n * DIM * sizeof(ushort);   // 25.6 MB (also y)
    ushort* h     = (ushort*)w;  w += (size_t)n * DIM * sizeof(ushort);   // 25.6 MB
    uint2*  bpair = (uint2*)w;   w += (size_t)E * sizeof(uint2);          // 12.8 MB
    ushort* wpk1  = (ushort*)w;  w += 32768 * sizeof(ushort);
    ushort* wpk2  = (ushort*)w;  w += 32768 * sizeof(ushort);
    float*  dinv  = (float*)w;   w += (size_t)n * sizeof(float);
    int*    rowptr= (int*)w;     w += (size_t)(n + 4) * sizeof(int);
    int*    col   = (int*)w;     w += (size_t)E * sizeof(int);            // 6.4 MB
    int*    bcnt  = (int*)w;     w += NBKT * sizeof(int);
    int*    bbase = (int*)w;     w += (NBKT + 4) * sizeof(int);
    int*    bcur  = (int*)w;     w += NBKT * sizeof(int);

    ushort* y = xb;  // safe alias: gemm reads its rows before storing them

    const int nbAgg  = (n + 3) / 4;
    const int ntiles = (n + 63) / 64;
    const int nbGemm = 512;
    const int nbCast = (n * DIM / 4 + 255) / 256;

    // ---- CSC + dinv (bucket pipeline) -------------------------------------
    hipMemsetAsync(bcnt, 0, NBKT * sizeof(int), stream);
    k_bcount  <<<64,   256, 0, stream>>>(dst, E, bcnt);
    k_bscan   <<<1,    256, 0, stream>>>(bcnt, bbase, bcur);
    k_bscatter<<<128,  256, 0, stream>>>(src, dst, E, bcur, bpair);
    k_bcsc    <<<NBKT, 256, 0, stream>>>(bpair, bbase, rowptr, dinv, col, n);

    // ---- precision prep ---------------------------------------------------
    k_split_w<<<64, 256, 0, stream>>>(W1, wpk1);
    k_split_w<<<64, 256, 0, stream>>>(W2, wpk2);
    k_cast_x<<<nbCast, 256, 0, stream>>>(x, xb, n * DIM / 4);

    // ---- layer 1 ----------------------------------------------------------
    k_gemm_mfma<<<nbGemm, 256, 0, stream>>>(xb, wpk1, dinv, y, n, ntiles);
    k_agg2<0><<<nbAgg, 256, 0, stream>>>(y, rowptr, col, dinv, b1, h, n);

    // ---- layer 2 ----------------------------------------------------------
    k_gemm_mfma<<<nbGemm, 256, 0, stream>>>(h, wpk2, dinv, y, n, ntiles);
    k_agg2<1><<<nbAgg, 256, 0, stream>>>(y, rowptr, col, dinv, b2, out, n);
}

// Round 7
// 428.304 us; speedup vs baseline: 1.8673x; 1.3053x over previous
//
#include <hip/hip_runtime.h>
#include <hip/hip_bf16.h>

// ---------------------------------------------------------------------------
// 2-layer GCN. MFMA bf16 GEMM (W hi+lo split), bf16 messages, bucket-built CSC.
//   dinv = rsqrt(deg+1);  y' = bf16( (x_bf16 @ (Whi+Wlo)) * dinv[row] )
//   agg[d] = y'[d] + sum y'[src];  h = relu(agg*dinv + b)
// CSC: bucket count -> scan -> write-combined bucket scatter -> per-bucket CSC.
// ---------------------------------------------------------------------------

#define DIM 128
#define BSH 9                    // bucket shift: 512 dst/bucket
#define NBKT 196                 // ceil(100000 / 512)

typedef __attribute__((ext_vector_type(8))) short bf16x8;
typedef __attribute__((ext_vector_type(4))) float f32x4;

// ---------------- bucket CSC pipeline --------------------------------------

// A: per-bucket edge counts (LDS histogram, one global atomic per bucket/block)
__global__ __launch_bounds__(256) void k_bcount(const int* __restrict__ dst,
                                                int E, int* __restrict__ bcnt) {
    __shared__ int h[NBKT];
    int t = threadIdx.x;
    for (int b = t; b < NBKT; b += 256) h[b] = 0;
    __syncthreads();
    for (int e = blockIdx.x * 256 + t; e < E; e += gridDim.x * 256)
        atomicAdd(&h[dst[e] >> BSH], 1);
    __syncthreads();
    for (int b = t; b < NBKT; b += 256)
        if (h[b]) atomicAdd(&bcnt[b], h[b]);
}

// B: exclusive scan of bcnt -> bbase[NBKT+1], init bcur
__global__ void k_bscan(const int* __restrict__ bcnt, int* __restrict__ bbase,
                        int* __restrict__ bcur) {
    __shared__ int a[256], c[256];
    int t = threadIdx.x;
    int v = (t < NBKT) ? bcnt[t] : 0;
    a[t] = v;
    __syncthreads();
    int* A = a; int* B = c;
    for (int off = 1; off < 256; off <<= 1) {
        B[t] = A[t] + (t >= off ? A[t - off] : 0);
        __syncthreads();
        int* tmp = A; A = B; B = tmp;
    }
    int incl = A[t];                 // 8 steps -> result back in 'a'
    if (t < NBKT) { int ex = incl - v; bbase[t] = ex; bcur[t] = ex; }
    if (t == NBKT - 1) bbase[NBKT] = incl;
}

// C: scatter (dst,src) pairs into bucket-grouped order, write-combined via LDS.
// 768 blocks, 1024-edge batches (4/thread), flag-gated flush of full buckets.
__global__ __launch_bounds__(256) void k_bscatter(
    const int* __restrict__ src, const int* __restrict__ dst, int E,
    int* __restrict__ bcur, uint2* __restrict__ out) {
    __shared__ uint2 stage[NBKT * 16];
    __shared__ int scnt[NBKT];
    __shared__ int needflush;
    int t = threadIdx.x;
    for (int b = t; b < NBKT; b += 256) scnt[b] = 0;
    if (t == 0) needflush = 0;
    __syncthreads();

    int per = (E + gridDim.x - 1) / gridDim.x;
    int s0 = blockIdx.x * per;
    int s1 = min(E, s0 + per);

    for (int base = s0; base < s1; base += 1024) {
#pragma unroll
        for (int k = 0; k < 4; ++k) {
            int e = base + t + k * 256;        // coalesced within each 256-chunk
            if (e < s1) {
                int d = dst[e];
                uint2 pr; pr.x = (uint)d; pr.y = (uint)src[e];
                int b = d >> BSH;
                int slot = atomicAdd(&scnt[b], 1);
                if (slot < 16) {
                    stage[b * 16 + slot] = pr;
                    if (slot == 15) needflush = 1;
                } else {                        // overflow: rare direct path
                    int c = atomicAdd(&bcur[b], 1);
                    out[c] = pr;
                }
            }
        }
        __syncthreads();
        if (needflush) {
            for (int bb = t; bb < NBKT; bb += 256) {
                if (scnt[bb] >= 16) {
                    int cur = atomicAdd(&bcur[bb], 16);
#pragma unroll
                    for (int k = 0; k < 16; ++k) out[cur + k] = stage[bb * 16 + k];
                    scnt[bb] = 0;               // extras beyond 16 went direct
                }
            }
            __syncthreads();
            if (t == 0) needflush = 0;
            __syncthreads();
        }
    }
    // tail: partial buckets (contiguous small chunks)
    for (int bb = t; bb < NBKT; bb += 256) {
        int c = scnt[bb]; if (c > 16) c = 16;
        if (c > 0) {
            int cur = atomicAdd(&bcur[bb], c);
            for (int k = 0; k < c; ++k) out[cur + k] = stage[bb * 16 + k];
        }
    }
}

// D: per bucket: local hist + scan -> rowptr/dinv (coalesced), col scatter
// within the bucket's contiguous window (write-combined in one L2).
__global__ __launch_bounds__(256) void k_bcsc(
    const uint2* __restrict__ pairs, const int* __restrict__ bbase,
    int* __restrict__ rowptr, float* __restrict__ dinv,
    int* __restrict__ col, int n) {
    __shared__ int lh[512], ls[512];
    int b = blockIdx.x, t = threadIdx.x;
    int p0 = bbase[b], p1 = bbase[b + 1];
    int d0 = b << BSH;

    lh[t] = 0; lh[t + 256] = 0;
    __syncthreads();
    for (int i = p0 + t; i < p1; i += 256)
        atomicAdd(&lh[pairs[i].x & 511], 1);
    __syncthreads();

    int deg0 = lh[t], deg1 = lh[t + 256];
    int* A = lh; int* B = ls;
    for (int off = 1; off < 512; off <<= 1) {      // 9 steps
        B[t]       = A[t]       + (t       >= off ? A[t - off]       : 0);
        B[t + 256] = A[t + 256] + (t + 256 >= off ? A[t + 256 - off] : 0);
        __syncthreads();
        int* tmp = A; A = B; B = tmp;
    }
    int ex0 = A[t] - deg0, ex1 = A[t + 256] - deg1;
    __syncthreads();
    B[t] = ex0; B[t + 256] = ex1;                  // cursors

    int nd = d0 + t;
    if (nd < n) { rowptr[nd] = p0 + ex0; dinv[nd] = rsqrtf((float)(deg0 + 1)); }
    nd = d0 + t + 256;
    if (nd < n) { rowptr[nd] = p0 + ex1; dinv[nd] = rsqrtf((float)(deg1 + 1)); }
    if (b == NBKT - 1 && t == 0) rowptr[n] = p1;
    __syncthreads();

    for (int i = p0 + t; i < p1; i += 256) {
        uint2 pr = pairs[i];
        int slot = p0 + atomicAdd(&B[pr.x & 511], 1);
        col[slot] = (int)pr.y;
    }
}

// ---------------- precision prep ------------------------------------------

__global__ void k_cast_x(const float* __restrict__ x, ushort* __restrict__ xb,
                         int total4) {
    int i = blockIdx.x * 256 + threadIdx.x;
    if (i < total4) {
        float4 v = ((const float4*)x)[i];
        __hip_bfloat16 a = __float2bfloat16(v.x), b = __float2bfloat16(v.y);
        __hip_bfloat16 c = __float2bfloat16(v.z), d = __float2bfloat16(v.w);
        ushort4 o = make_ushort4(*(ushort*)&a, *(ushort*)&b,
                                 *(ushort*)&c, *(ushort*)&d);
        ((ushort4*)xb)[i] = o;
    }
}

// W [128][128] f32 -> packed MFMA B-fragments, hi+lo split.
// Wpk (ushort): [term(2)][ct(8)][ks(4)][lane(64)][j(8)]
// B[k = ks*32 + (lane>>4)*8 + j][n = ct*16 + (lane&15)]
__global__ void k_split_w(const float* __restrict__ W, ushort* __restrict__ Wpk) {
    int idx = blockIdx.x * 256 + threadIdx.x;   // 0..16383
    if (idx >= 16384) return;
    int j    = idx & 7;
    int lane = (idx >> 3) & 63;
    int ks   = (idx >> 9) & 3;
    int ct   = idx >> 11;
    int k  = ks * 32 + (lane >> 4) * 8 + j;
    int nn = ct * 16 + (lane & 15);
    float w = W[k * 128 + nn];
    __hip_bfloat16 hi = __float2bfloat16(w);
    float rem = w - __bfloat162float(hi);
    __hip_bfloat16 lo = __float2bfloat16(rem);
    Wpk[idx]         = *(ushort*)&hi;
    Wpk[16384 + idx] = *(ushort*)&lo;
}

// ---------------- MFMA GEMM: y = bf16( (xb @ (Whi+Wlo)) * dinv[row] ) ------
__global__ __launch_bounds__(256, 2) void k_gemm_mfma(
    const ushort* __restrict__ xb, const ushort* __restrict__ Wpk,
    const float* __restrict__ dinv, ushort* __restrict__ y,
    int n, int ntiles) {
    __shared__ ushort Wl[32768];
    int t = threadIdx.x;
    {
        const uint4* s4 = (const uint4*)Wpk;
        uint4* d4 = (uint4*)Wl;
#pragma unroll
        for (int i = 0; i < 16; ++i) d4[t + 256 * i] = s4[t + 256 * i];
    }
    __syncthreads();

    const int wave = t >> 6, lane = t & 63;
    const int l15 = lane & 15, lg = lane >> 4;

    for (int tile = blockIdx.x; tile < ntiles; tile += gridDim.x) {
        int row0 = tile * 64 + wave * 16;
        int arow = row0 + l15;
        if (arow >= n) arow = n - 1;
        const ushort* xp = xb + (size_t)arow * 128 + lg * 8;

        bf16x8 a[4];
#pragma unroll
        for (int ks = 0; ks < 4; ++ks)
            a[ks] = *(const bf16x8*)(xp + ks * 32);

        f32x4 acc[8];
#pragma unroll
        for (int ct = 0; ct < 8; ++ct) acc[ct] = (f32x4)(0.f);

#pragma unroll
        for (int ks = 0; ks < 4; ++ks) {
#pragma unroll
            for (int ct = 0; ct < 8; ++ct) {
                bf16x8 b = *(const bf16x8*)&Wl[(size_t)((0 * 8 + ct) * 4 + ks) * 512 + lane * 8];
                acc[ct] = __builtin_amdgcn_mfma_f32_16x16x32_bf16(a[ks], b, acc[ct], 0, 0, 0);
            }
#pragma unroll
            for (int ct = 0; ct < 8; ++ct) {
                bf16x8 b = *(const bf16x8*)&Wl[(size_t)((1 * 8 + ct) * 4 + ks) * 512 + lane * 8];
                acc[ct] = __builtin_amdgcn_mfma_f32_16x16x32_bf16(a[ks], b, acc[ct], 0, 0, 0);
            }
        }

#pragma unroll
        for (int r = 0; r < 4; ++r) {
            int row = row0 + lg * 4 + r;
            if (row < n) {
                float dv = dinv[row];
                ushort* yr = y + (size_t)row * 128 + l15;
#pragma unroll
                for (int ct = 0; ct < 8; ++ct) {
                    __hip_bfloat16 h = __float2bfloat16(acc[ct][r] * dv);
                    yr[ct * 16] = *(ushort*)&h;
                }
            }
        }
    }
}

// ---------------- aggregation: full wave per node, 4 gathers in flight -----
template <int MODE>   // 0: bf16 out, 1: f32 out
__global__ __launch_bounds__(256) void k_agg2(
    const ushort* __restrict__ yb, const int* __restrict__ rowptr,
    const int* __restrict__ col, const float* __restrict__ dinv,
    const float* __restrict__ bias, void* __restrict__ outp, int n) {
    int t = threadIdx.x, lane = t & 63;
    int node = blockIdx.x * 4 + (t >> 6);
    if (node >= n) return;

    uint v0 = *(const uint*)(yb + (size_t)node * 128 + lane * 2);   // self loop
    float ax = __uint_as_float(v0 << 16);
    float ay = __uint_as_float(v0 & 0xffff0000u);

    int lo = rowptr[node], hi = rowptr[node + 1];
    int i = lo;
    for (; i + 4 <= hi; i += 4) {
        int s0 = col[i], s1 = col[i + 1], s2 = col[i + 2], s3 = col[i + 3];
        uint w0 = *(const uint*)(yb + (size_t)s0 * 128 + lane * 2);
        uint w1 = *(const uint*)(yb + (size_t)s1 * 128 + lane * 2);
        uint w2 = *(const uint*)(yb + (size_t)s2 * 128 + lane * 2);
        uint w3 = *(const uint*)(yb + (size_t)s3 * 128 + lane * 2);
        ax += __uint_as_float(w0 << 16);         ay += __uint_as_float(w0 & 0xffff0000u);
        ax += __uint_as_float(w1 << 16);         ay += __uint_as_float(w1 & 0xffff0000u);
        ax += __uint_as_float(w2 << 16);         ay += __uint_as_float(w2 & 0xffff0000u);
        ax += __uint_as_float(w3 << 16);         ay += __uint_as_float(w3 & 0xffff0000u);
    }
    for (; i < hi; ++i) {
        int s = col[i];
        uint w = *(const uint*)(yb + (size_t)s * 128 + lane * 2);
        ax += __uint_as_float(w << 16);
        ay += __uint_as_float(w & 0xffff0000u);
    }

    float dv = dinv[node];
    float2 b = ((const float2*)bias)[lane];
    float ox = fmaxf(ax * dv + b.x, 0.f);
    float oy = fmaxf(ay * dv + b.y, 0.f);

    if (MODE == 0) {
        __hip_bfloat16 ha = __float2bfloat16(ox), hb = __float2bfloat16(oy);
        uint o = ((uint)(*(ushort*)&hb) << 16) | (uint)(*(ushort*)&ha);
        ((uint*)outp)[(size_t)node * 64 + lane] = o;
    } else {
        ((float2*)outp)[(size_t)node * 64 + lane] = make_float2(ox, oy);
    }
}

// ---------------------------------------------------------------------------

extern "C" void kernel_launch(void* const* d_in, const int* in_sizes, int n_in,
                              void* d_out, int out_size, void* d_ws, size_t ws_size,
                              hipStream_t stream) {
    const float* x  = (const float*)d_in[0];
    const float* W1 = (const float*)d_in[1];
    const float* b1 = (const float*)d_in[2];
    const float* W2 = (const float*)d_in[3];
    const float* b2 = (const float*)d_in[4];
    const int*   ei = (const int*)d_in[5];

    const int n = in_sizes[0] / DIM;     // 100000
    const int E = in_sizes[5] / 2;       // 1600000
    const int* src = ei;
    const int* dst = ei + E;
    float* out = (float*)d_out;

    // workspace carve-up
    char* w = (char*)d_ws;
    ushort* xb    = (ushort*)w;  w += (size_t)n * DIM * sizeof(ushort);   // 25.6 MB (also y)
    ushort* h     = (ushort*)w;  w += (size_t)n * DIM * sizeof(ushort);   // 25.6 MB
    uint2*  bpair = (uint2*)w;   w += (size_t)E * sizeof(uint2);          // 12.8 MB
    ushort* wpk1  = (ushort*)w;  w += 32768 * sizeof(ushort);
    ushort* wpk2  = (ushort*)w;  w += 32768 * sizeof(ushort);
    float*  dinv  = (float*)w;   w += (size_t)n * sizeof(float);
    int*    rowptr= (int*)w;     w += (size_t)(n + 4) * sizeof(int);
    int*    col   = (int*)w;     w += (size_t)E * sizeof(int);            // 6.4 MB
    int*    bcnt  = (int*)w;     w += NBKT * sizeof(int);
    int*    bbase = (int*)w;     w += (NBKT + 4) * sizeof(int);
    int*    bcur  = (int*)w;     w += NBKT * sizeof(int);

    ushort* y = xb;  // safe alias: gemm reads its rows before storing them

    const int nbAgg  = (n + 3) / 4;
    const int ntiles = (n + 63) / 64;
    const int nbGemm = 512;
    const int nbCast = (n * DIM / 4 + 255) / 256;

    // ---- CSC + dinv (bucket pipeline) -------------------------------------
    hipMemsetAsync(bcnt, 0, NBKT * sizeof(int), stream);
    k_bcount  <<<256,  256, 0, stream>>>(dst, E, bcnt);
    k_bscan   <<<1,    256, 0, stream>>>(bcnt, bbase, bcur);
    k_bscatter<<<768,  256, 0, stream>>>(src, dst, E, bcur, bpair);
    k_bcsc    <<<NBKT, 256, 0, stream>>>(bpair, bbase, rowptr, dinv, col, n);

    // ---- precision prep ---------------------------------------------------
    k_split_w<<<64, 256, 0, stream>>>(W1, wpk1);
    k_split_w<<<64, 256, 0, stream>>>(W2, wpk2);
    k_cast_x<<<nbCast, 256, 0, stream>>>(x, xb, n * DIM / 4);

    // ---- layer 1 ----------------------------------------------------------
    k_gemm_mfma<<<nbGemm, 256, 0, stream>>>(xb, wpk1, dinv, y, n, ntiles);
    k_agg2<0><<<nbAgg, 256, 0, stream>>>(y, rowptr, col, dinv, b1, h, n);

    // ---- layer 2 ----------------------------------------------------------
    k_gemm_mfma<<<nbGemm, 256, 0, stream>>>(h, wpk2, dinv, y, n, ntiles);
    k_agg2<1><<<nbAgg, 256, 0, stream>>>(y, rowptr, col, dinv, b2, out, n);
}

// Round 8
// 370.964 us; speedup vs baseline: 2.1560x; 1.1546x over previous
//
#include <hip/hip_runtime.h>
#include <hip/hip_bf16.h>

// ---------------------------------------------------------------------------
// 2-layer GCN. MFMA bf16 GEMM (W hi+lo split, f32 input fused for layer 1),
// bf16 messages, bucket-built CSC with packed uint edges.
//   dinv = rsqrt(deg+1);  y' = bf16( (x @ (Whi+Wlo)) * dinv[row] )
//   agg[d] = y'[d] + sum y'[src];  h = relu(agg*dinv + b)
// ---------------------------------------------------------------------------

#define DIM 128
#define BSH 9                    // bucket shift: 512 dst/bucket
#define NBKT 196                 // ceil(100000 / 512)

typedef __attribute__((ext_vector_type(8))) short bf16x8;
typedef __attribute__((ext_vector_type(4))) float f32x4;

static __device__ __forceinline__ ushort bfbits(float f) {
    __hip_bfloat16 h = __float2bfloat16(f);
    return *(ushort*)&h;
}

// ---------------- bucket CSC pipeline --------------------------------------

__global__ __launch_bounds__(256) void k_bcount(const int* __restrict__ dst,
                                                int E, int* __restrict__ bcnt) {
    __shared__ int h[NBKT];
    int t = threadIdx.x;
    for (int b = t; b < NBKT; b += 256) h[b] = 0;
    __syncthreads();
    for (int e = blockIdx.x * 256 + t; e < E; e += gridDim.x * 256)
        atomicAdd(&h[dst[e] >> BSH], 1);
    __syncthreads();
    for (int b = t; b < NBKT; b += 256)
        if (h[b]) atomicAdd(&bcnt[b], h[b]);
}

__global__ void k_bscan(const int* __restrict__ bcnt, int* __restrict__ bbase,
                        int* __restrict__ bcur) {
    __shared__ int a[256], c[256];
    int t = threadIdx.x;
    int v = (t < NBKT) ? bcnt[t] : 0;
    a[t] = v;
    __syncthreads();
    int* A = a; int* B = c;
    for (int off = 1; off < 256; off <<= 1) {
        B[t] = A[t] + (t >= off ? A[t - off] : 0);
        __syncthreads();
        int* tmp = A; A = B; B = tmp;
    }
    int incl = A[t];
    if (t < NBKT) { int ex = incl - v; bbase[t] = ex; bcur[t] = ex; }
    if (t == NBKT - 1) bbase[NBKT] = incl;
}

// C: scatter packed edges (dstLocal<<17 | src) into bucket-grouped order.
// 768 blocks, 1024-edge batches, 32-entry (128B) write-combined flush chunks.
__global__ __launch_bounds__(256) void k_bscatter(
    const int* __restrict__ src, const int* __restrict__ dst, int E,
    int* __restrict__ bcur, uint* __restrict__ out) {
    __shared__ uint stage[NBKT * 32];
    __shared__ int scnt[NBKT];
    __shared__ int needflush;
    int t = threadIdx.x;
    for (int b = t; b < NBKT; b += 256) scnt[b] = 0;
    if (t == 0) needflush = 0;
    __syncthreads();

    int per = (E + gridDim.x - 1) / gridDim.x;
    int s0 = blockIdx.x * per;
    int s1 = min(E, s0 + per);

    for (int base = s0; base < s1; base += 1024) {
#pragma unroll
        for (int k = 0; k < 4; ++k) {
            int e = base + t + k * 256;
            if (e < s1) {
                int d = dst[e];
                uint pr = ((uint)(d & 511) << 17) | (uint)src[e];
                int b = d >> BSH;
                int slot = atomicAdd(&scnt[b], 1);
                if (slot < 32) {
                    stage[b * 32 + slot] = pr;
                    if (slot == 31) needflush = 1;
                } else {                        // rare overflow: direct path
                    int c = atomicAdd(&bcur[b], 1);
                    out[c] = pr;
                }
            }
        }
        __syncthreads();
        if (needflush) {
            for (int bb = t; bb < NBKT; bb += 256) {
                if (scnt[bb] >= 32) {
                    int cur = atomicAdd(&bcur[bb], 32);
#pragma unroll
                    for (int k = 0; k < 32; ++k) out[cur + k] = stage[bb * 32 + k];
                    scnt[bb] = 0;
                }
            }
            __syncthreads();
            if (t == 0) needflush = 0;
            __syncthreads();
        }
    }
    for (int bb = t; bb < NBKT; bb += 256) {
        int c = scnt[bb]; if (c > 32) c = 32;
        if (c > 0) {
            int cur = atomicAdd(&bcur[bb], c);
            for (int k = 0; k < c; ++k) out[cur + k] = stage[bb * 32 + k];
        }
    }
}

// D: per bucket: local hist + scan -> rowptr/dinv, col scatter in-window.
__global__ __launch_bounds__(256) void k_bcsc(
    const uint* __restrict__ pairs, const int* __restrict__ bbase,
    int* __restrict__ rowptr, float* __restrict__ dinv,
    int* __restrict__ col, int n) {
    __shared__ int lh[512], ls[512];
    int b = blockIdx.x, t = threadIdx.x;
    int p0 = bbase[b], p1 = bbase[b + 1];
    int d0 = b << BSH;

    lh[t] = 0; lh[t + 256] = 0;
    __syncthreads();
    for (int i = p0 + t; i < p1; i += 256)
        atomicAdd(&lh[pairs[i] >> 17], 1);
    __syncthreads();

    int deg0 = lh[t], deg1 = lh[t + 256];
    int* A = lh; int* B = ls;
    for (int off = 1; off < 512; off <<= 1) {
        B[t]       = A[t]       + (t       >= off ? A[t - off]       : 0);
        B[t + 256] = A[t + 256] + (t + 256 >= off ? A[t + 256 - off] : 0);
        __syncthreads();
        int* tmp = A; A = B; B = tmp;
    }
    int ex0 = A[t] - deg0, ex1 = A[t + 256] - deg1;
    __syncthreads();
    B[t] = ex0; B[t + 256] = ex1;                  // cursors

    int nd = d0 + t;
    if (nd < n) { rowptr[nd] = p0 + ex0; dinv[nd] = rsqrtf((float)(deg0 + 1)); }
    nd = d0 + t + 256;
    if (nd < n) { rowptr[nd] = p0 + ex1; dinv[nd] = rsqrtf((float)(deg1 + 1)); }
    if (b == NBKT - 1 && t == 0) rowptr[n] = p1;
    __syncthreads();

    for (int i = p0 + t; i < p1; i += 256) {
        uint pr = pairs[i];
        int slot = p0 + atomicAdd(&B[pr >> 17], 1);
        col[slot] = (int)(pr & 0x1FFFFu);
    }
}

// ---------------- W prep: both layers in one launch ------------------------
// Wpk (ushort): [term(2)][ct(8)][ks(4)][lane(64)][j(8)]
// B[k = ks*32 + (lane>>4)*8 + j][n = ct*16 + (lane&15)]
__global__ void k_split_w2(const float* __restrict__ W1,
                           const float* __restrict__ W2,
                           ushort* __restrict__ wpk1,
                           ushort* __restrict__ wpk2) {
    int g = blockIdx.x;
    const float* W   = (g < 64) ? W1 : W2;
    ushort* Wpk      = (g < 64) ? wpk1 : wpk2;
    int idx = (g & 63) * 256 + threadIdx.x;     // 0..16383
    int j    = idx & 7;
    int lane = (idx >> 3) & 63;
    int ks   = (idx >> 9) & 3;
    int ct   = idx >> 11;
    int k  = ks * 32 + (lane >> 4) * 8 + j;
    int nn = ct * 16 + (lane & 15);
    float w = W[k * 128 + nn];
    __hip_bfloat16 hi = __float2bfloat16(w);
    float rem = w - __bfloat162float(hi);
    Wpk[idx]         = *(ushort*)&hi;
    Wpk[16384 + idx] = bfbits(rem);
}

// ---------------- MFMA GEMM: y = bf16( (x @ (Whi+Wlo)) * dinv[row] ) -------
// INF32=1: input f32 (layer 1, converts in-register); 0: input bf16.
template <int INF32>
__global__ __launch_bounds__(256, 2) void k_gemm_mfma(
    const void* __restrict__ xin, const ushort* __restrict__ Wpk,
    const float* __restrict__ dinv, ushort* __restrict__ y,
    int n, int ntiles) {
    __shared__ ushort Wl[32768];
    int t = threadIdx.x;
    {
        const uint4* s4 = (const uint4*)Wpk;
        uint4* d4 = (uint4*)Wl;
#pragma unroll
        for (int i = 0; i < 16; ++i) d4[t + 256 * i] = s4[t + 256 * i];
    }
    __syncthreads();

    const int wave = t >> 6, lane = t & 63;
    const int l15 = lane & 15, lg = lane >> 4;

    for (int tile = blockIdx.x; tile < ntiles; tile += gridDim.x) {
        int row0 = tile * 64 + wave * 16;
        int arow = row0 + l15;
        if (arow >= n) arow = n - 1;

        bf16x8 a[4];
        if (INF32) {
            const float* xp = (const float*)xin + (size_t)arow * 128 + lg * 8;
#pragma unroll
            for (int ks = 0; ks < 4; ++ks) {
                float4 f0 = *(const float4*)(xp + ks * 32);
                float4 f1 = *(const float4*)(xp + ks * 32 + 4);
                bf16x8 av;
                av[0] = (short)bfbits(f0.x); av[1] = (short)bfbits(f0.y);
                av[2] = (short)bfbits(f0.z); av[3] = (short)bfbits(f0.w);
                av[4] = (short)bfbits(f1.x); av[5] = (short)bfbits(f1.y);
                av[6] = (short)bfbits(f1.z); av[7] = (short)bfbits(f1.w);
                a[ks] = av;
            }
        } else {
            const ushort* xp = (const ushort*)xin + (size_t)arow * 128 + lg * 8;
#pragma unroll
            for (int ks = 0; ks < 4; ++ks)
                a[ks] = *(const bf16x8*)(xp + ks * 32);
        }

        f32x4 acc[8];
#pragma unroll
        for (int ct = 0; ct < 8; ++ct) acc[ct] = (f32x4)(0.f);

#pragma unroll
        for (int ks = 0; ks < 4; ++ks) {
#pragma unroll
            for (int ct = 0; ct < 8; ++ct) {
                bf16x8 b = *(const bf16x8*)&Wl[(size_t)((0 * 8 + ct) * 4 + ks) * 512 + lane * 8];
                acc[ct] = __builtin_amdgcn_mfma_f32_16x16x32_bf16(a[ks], b, acc[ct], 0, 0, 0);
            }
#pragma unroll
            for (int ct = 0; ct < 8; ++ct) {
                bf16x8 b = *(const bf16x8*)&Wl[(size_t)((1 * 8 + ct) * 4 + ks) * 512 + lane * 8];
                acc[ct] = __builtin_amdgcn_mfma_f32_16x16x32_bf16(a[ks], b, acc[ct], 0, 0, 0);
            }
        }

#pragma unroll
        for (int r = 0; r < 4; ++r) {
            int row = row0 + lg * 4 + r;
            if (row < n) {
                float dv = dinv[row];
                ushort* yr = y + (size_t)row * 128 + l15;
#pragma unroll
                for (int ct = 0; ct < 8; ++ct)
                    yr[ct * 16] = bfbits(acc[ct][r] * dv);
            }
        }
    }
}

// ---------------- aggregation: full wave per node, 8 gathers in flight -----
template <int MODE>   // 0: bf16 out, 1: f32 out
__global__ __launch_bounds__(256) void k_agg2(
    const ushort* __restrict__ yb, const int* __restrict__ rowptr,
    const int* __restrict__ col, const float* __restrict__ dinv,
    const float* __restrict__ bias, void* __restrict__ outp, int n) {
    int t = threadIdx.x, lane = t & 63;
    int node = __builtin_amdgcn_readfirstlane(blockIdx.x * 4 + (t >> 6));
    if (node >= n) return;

    uint v0 = *(const uint*)(yb + (size_t)node * 128 + lane * 2);   // self loop
    float ax = __uint_as_float(v0 << 16);
    float ay = __uint_as_float(v0 & 0xffff0000u);

    int lo = rowptr[node], hi = rowptr[node + 1];
    int i = lo;
    for (; i + 8 <= hi; i += 8) {
        uint w[8];
#pragma unroll
        for (int k = 0; k < 8; ++k)
            w[k] = *(const uint*)(yb + (size_t)col[i + k] * 128 + lane * 2);
#pragma unroll
        for (int k = 0; k < 8; ++k) {
            ax += __uint_as_float(w[k] << 16);
            ay += __uint_as_float(w[k] & 0xffff0000u);
        }
    }
    for (; i + 4 <= hi; i += 4) {
        uint w[4];
#pragma unroll
        for (int k = 0; k < 4; ++k)
            w[k] = *(const uint*)(yb + (size_t)col[i + k] * 128 + lane * 2);
#pragma unroll
        for (int k = 0; k < 4; ++k) {
            ax += __uint_as_float(w[k] << 16);
            ay += __uint_as_float(w[k] & 0xffff0000u);
        }
    }
    for (; i < hi; ++i) {
        uint w = *(const uint*)(yb + (size_t)col[i] * 128 + lane * 2);
        ax += __uint_as_float(w << 16);
        ay += __uint_as_float(w & 0xffff0000u);
    }

    float dv = dinv[node];
    float2 b = ((const float2*)bias)[lane];
    float ox = fmaxf(ax * dv + b.x, 0.f);
    float oy = fmaxf(ay * dv + b.y, 0.f);

    if (MODE == 0) {
        uint o = ((uint)bfbits(oy) << 16) | (uint)bfbits(ox);
        ((uint*)outp)[(size_t)node * 64 + lane] = o;
    } else {
        ((float2*)outp)[(size_t)node * 64 + lane] = make_float2(ox, oy);
    }
}

// ---------------------------------------------------------------------------

extern "C" void kernel_launch(void* const* d_in, const int* in_sizes, int n_in,
                              void* d_out, int out_size, void* d_ws, size_t ws_size,
                              hipStream_t stream) {
    const float* x  = (const float*)d_in[0];
    const float* W1 = (const float*)d_in[1];
    const float* b1 = (const float*)d_in[2];
    const float* W2 = (const float*)d_in[3];
    const float* b2 = (const float*)d_in[4];
    const int*   ei = (const int*)d_in[5];

    const int n = in_sizes[0] / DIM;     // 100000
    const int E = in_sizes[5] / 2;       // 1600000
    const int* src = ei;
    const int* dst = ei + E;
    float* out = (float*)d_out;

    // workspace carve-up
    char* w = (char*)d_ws;
    ushort* y     = (ushort*)w;  w += (size_t)n * DIM * sizeof(ushort);   // 25.6 MB
    ushort* h     = (ushort*)w;  w += (size_t)n * DIM * sizeof(ushort);   // 25.6 MB
    uint*   bpair = (uint*)w;    w += (size_t)E * sizeof(uint);           // 6.4 MB
    ushort* wpk1  = (ushort*)w;  w += 32768 * sizeof(ushort);
    ushort* wpk2  = (ushort*)w;  w += 32768 * sizeof(ushort);
    float*  dinv  = (float*)w;   w += (size_t)n * sizeof(float);
    int*    rowptr= (int*)w;     w += (size_t)(n + 4) * sizeof(int);
    int*    col   = (int*)w;     w += (size_t)E * sizeof(int);            // 6.4 MB
    int*    bcnt  = (int*)w;     w += NBKT * sizeof(int);
    int*    bbase = (int*)w;     w += (NBKT + 4) * sizeof(int);
    int*    bcur  = (int*)w;     w += NBKT * sizeof(int);

    const int nbAgg  = (n + 3) / 4;
    const int ntiles = (n + 63) / 64;
    const int nbGemm = 512;

    // ---- CSC + dinv (bucket pipeline, packed uint edges) ------------------
    hipMemsetAsync(bcnt, 0, NBKT * sizeof(int), stream);
    k_bcount  <<<256,  256, 0, stream>>>(dst, E, bcnt);
    k_bscan   <<<1,    256, 0, stream>>>(bcnt, bbase, bcur);
    k_bscatter<<<768,  256, 0, stream>>>(src, dst, E, bcur, bpair);
    k_bcsc    <<<NBKT, 256, 0, stream>>>(bpair, bbase, rowptr, dinv, col, n);

    // ---- W prep -----------------------------------------------------------
    k_split_w2<<<128, 256, 0, stream>>>(W1, W2, wpk1, wpk2);

    // ---- layer 1 (f32 input fused into GEMM) ------------------------------
    k_gemm_mfma<1><<<nbGemm, 256, 0, stream>>>(x, wpk1, dinv, y, n, ntiles);
    k_agg2<0><<<nbAgg, 256, 0, stream>>>(y, rowptr, col, dinv, b1, h, n);

    // ---- layer 2 ----------------------------------------------------------
    k_gemm_mfma<0><<<nbGemm, 256, 0, stream>>>(h, wpk2, dinv, y, n, ntiles);
    k_agg2<1><<<nbAgg, 256, 0, stream>>>(y, rowptr, col, dinv, b2, out, n);
}